// Round 1
// 248.214 us; speedup vs baseline: 1.0099x; 1.0099x over previous
//
#include <hip/hip_runtime.h>
#include <hip/hip_bf16.h>
#include <hip/hip_fp16.h>

#define N_NODES 50000
#define N_EDGES 800000
#define DIM 128
#define NGROUPS (N_NODES / 16)                 // 3125 (exact)
#define LROW2 132                              // LDS row stride (floats)
#define KBUCKET 196                            // buckets of 256 nodes (dst>>8)
#define BCAP 5120                              // bucket capacity (mean 4096, ~16 sigma)
#define EPB 2000                               // edges per phase-A block (400 blocks)

typedef __attribute__((ext_vector_type(8))) _Float16 hfrag8;
typedef __attribute__((ext_vector_type(4))) float f32x4;
typedef _Float16 h2 __attribute__((ext_vector_type(2)));

__device__ __forceinline__ h2 u2h(uint u){ union{uint u; h2 h;} c; c.u = u; return c.h; }

// ---------------- CSR build: two-phase bucket radix ----------------
// bucketdata entry packed: (src << 8) | (dst & 255)   [src < 65536 fits 16b]

__global__ __launch_bounds__(256) void bucket_scatter_k(
    const int* __restrict__ src, const int* __restrict__ dst,
    int* __restrict__ bucket_cnt, uint* __restrict__ bucketdata)
{
  __shared__ int cnt[KBUCKET], base[KBUCKET], cur[KBUCKET];
  int tid = threadIdx.x;
  for (int t = tid; t < KBUCKET; t += 256) { cnt[t] = 0; cur[t] = 0; }
  __syncthreads();
  int e0 = blockIdx.x * EPB;
  for (int i = tid; i < EPB; i += 256)
    atomicAdd(&cnt[dst[e0 + i] >> 8], 1);
  __syncthreads();
  for (int t = tid; t < KBUCKET; t += 256)
    base[t] = atomicAdd(&bucket_cnt[t], cnt[t]);
  __syncthreads();
  for (int i = tid; i < EPB; i += 256) {
    int s = src[e0 + i], d = dst[e0 + i];
    int b = d >> 8;
    int r = atomicAdd(&cur[b], 1);
    bucketdata[(size_t)b * BCAP + base[b] + r] = ((uint)s << 8) | (uint)(d & 255);
  }
}

__global__ __launch_bounds__(256) void bucket_csr_k(
    const int* __restrict__ bucket_cnt, const uint* __restrict__ bucketdata,
    int* __restrict__ row_start, int* __restrict__ csr_src)
{
  __shared__ int hist[256], cur[256];
  __shared__ int wsumA[4], wsumB[4];
  int b = blockIdx.x, tid = threadIdx.x;
  int lane = tid & 63, w = tid >> 6;
  int vv = (tid < b) ? bucket_cnt[tid] : 0;
  #pragma unroll
  for (int off = 32; off > 0; off >>= 1) vv += __shfl_xor(vv, off, 64);
  if (lane == 0) wsumA[w] = vv;
  hist[tid] = 0;
  __syncthreads();
  int base_csr = wsumA[0] + wsumA[1] + wsumA[2] + wsumA[3];
  int cnt = bucket_cnt[b];
  int node0 = b << 8;
  const uint* bd = bucketdata + (size_t)b * BCAP;
  for (int i = tid; i < cnt; i += 256)
    atomicAdd(&hist[bd[i] & 255], 1);
  __syncthreads();
  int v = hist[tid];
  int inc = v;
  #pragma unroll
  for (int off = 1; off < 64; off <<= 1) {
    int y = __shfl_up(inc, off, 64);
    if (lane >= off) inc += y;
  }
  if (lane == 63) wsumB[w] = inc;
  __syncthreads();
  int wpre = 0;
  #pragma unroll
  for (int i = 0; i < 4; i++) if (i < w) wpre += wsumB[i];
  int excl = wpre + inc - v;
  int node = node0 + tid;
  if (node < N_NODES) row_start[node] = base_csr + excl;
  if (b == 0 && tid == 0) row_start[N_NODES] = N_EDGES;
  cur[tid] = excl;
  __syncthreads();
  for (int i = tid; i < cnt; i += 256) {
    uint p = bd[i];
    int r = atomicAdd(&cur[p & 255], 1);
    csr_src[base_csr + r] = (int)(p >> 8);
  }
}

// ---------------- W fragment prep (fp16) + bucket_cnt zeroing ----------------
// B-frag: lane holds B[k=(lane>>4)*8+j][n=lane&15].
__global__ __launch_bounds__(64) void prep_w(
    const float* __restrict__ Wl1, const float* __restrict__ Wr1,
    const float* __restrict__ Wl2, const float* __restrict__ Wr2,
    _Float16* __restrict__ wb, int* __restrict__ bucket_cnt)
{
  int bid = blockIdx.x;            // 2 layers * 4 C * 16 g = 128 blocks
  if (bid == 0) {                  // fold the memset dispatch in here
    for (int t = threadIdx.x; t < KBUCKET; t += 64) bucket_cnt[t] = 0;
  }
  int layer = bid >> 6, rest = bid & 63;
  int C = rest >> 4, g = rest & 15;
  int lane = threadIdx.x;
  int m = lane & 15, q = lane >> 4;
  int dim = g*16 + m;
  const float* W = layer ? (dim < 128 ? Wl2 : Wr2) : (dim < 128 ? Wl1 : Wr1);
  int dcol = dim & 127;
  _Float16 h[8];
  #pragma unroll
  for (int j = 0; j < 8; j++) {
    int k = C*32 + q*8 + j;
    h[j] = (_Float16)W[(size_t)k*DIM + dcol];
  }
  size_t off = ((size_t)bid*64 + lane)*8;
  *(hfrag8*)(wb + off) = *(hfrag8*)h;
}

// ---------------- MFMA dual GEMM (fp16 single-MFMA) ----------------
// Wave = 16 nodes x 256 combined dims. One f16 MFMA per 16x16 tile.
// TIN=float: cvt x on the fly. TIN=_Float16: raw uint4 frag loads.
template<typename TIN>
__global__ __launch_bounds__(256) void gemm_mfma(
    const TIN* __restrict__ x,
    const _Float16* __restrict__ wb,
    const float* __restrict__ bl, const float* __restrict__ br,
    __half* __restrict__ xlh, __half* __restrict__ xrh)
{
  __shared__ float lds[4][16*LROW2];   // 33.8 KB
  int wv = threadIdx.x >> 6, lane = threadIdx.x & 63;
  int G = blockIdx.x * 4 + wv;
  if (G >= NGROUPS) return;

  int m = lane & 15, q = lane >> 4;
  const TIN* xrow = x + (size_t)(G*16 + m)*DIM + q*8;

  f32x4 acc[16];
  #pragma unroll
  for (int g = 0; g < 16; g++) acc[g] = (f32x4)(0.f);

  #pragma unroll 1
  for (int C = 0; C < 4; C++) {
    hfrag8 ah;
    if constexpr (sizeof(TIN) == 4) {
      float v[8];
      *(float4*)(v)     = *(const float4*)((const float*)xrow + C*32);
      *(float4*)(v + 4) = *(const float4*)((const float*)xrow + C*32 + 4);
      _Float16 hh[8];
      #pragma unroll
      for (int j = 0; j < 8; j++) hh[j] = (_Float16)v[j];
      ah = *(hfrag8*)hh;
    } else {
      ah = *(const hfrag8*)((const _Float16*)xrow + C*32);
    }
    #pragma unroll
    for (int g = 0; g < 16; g++) {
      size_t boff = ((size_t)(C*16 + g)*64 + lane)*8;
      hfrag8 bh = *(const hfrag8*)(wb + boff);
      acc[g] = __builtin_amdgcn_mfma_f32_16x16x32_f16(ah, bh, acc[g], 0, 0, 0);
    }
  }

  // C/D: col = lane&15 (dim), row = (lane>>4)*4 + reg (node). LDS transpose.
  float* wlds = lds[wv];
  int dcol = (lane & 31) * 4;
  int rowsel = lane >> 5;
  #pragma unroll
  for (int half = 0; half < 2; half++) {
    #pragma unroll
    for (int g = 0; g < 8; g++) {
      #pragma unroll
      for (int r = 0; r < 4; r++)
        wlds[(q*4 + r)*LROW2 + g*16 + m] = acc[half*8 + g][r];
    }
    const float* B = half ? br : bl;
    ushort* outh = half ? (ushort*)xrh : (ushort*)xlh;
    float4 bv = *(const float4*)(B + dcol);
    #pragma unroll
    for (int it = 0; it < 8; it++) {
      int i = it*2 + rowsel;
      float4 vv = *(const float4*)(wlds + i*LROW2 + dcol);
      int node = G*16 + i;
      __half2 h0 = __floats2half2_rn(vv.x + bv.x, vv.y + bv.y);
      __half2 h1 = __floats2half2_rn(vv.z + bv.z, vv.w + bv.w);
      uint2 pk = make_uint2(*(uint*)&h0, *(uint*)&h1);
      *(uint2*)(outh + (size_t)node*DIM + dcol) = pk;
    }
  }
}

// ---------------- fused edge phase: 16 lanes/node, 4 nodes/wave ------------
// Packed fp16 math; OUT==1 writes fp16 rows (next layer input), OUT==0 fp32.
// Per-group loop bound (divergent) + 8-deep gather pipeline.
template<int OUT>
__global__ __launch_bounds__(256) void gat_gather(
    const __half* __restrict__ xlh, const __half* __restrict__ xrh,
    const int* __restrict__ row_start, const int* __restrict__ csr_src,
    const float* __restrict__ att, const float* __restrict__ bias,
    float* __restrict__ outf, __half* __restrict__ outh)
{
  int wave = (blockIdx.x * 256 + threadIdx.x) >> 6;
  int lane = threadIdx.x & 63;
  int q4 = lane >> 4;
  int hl = lane & 15;
  int node = wave * 4 + q4;           // N = 50000 = 12500 waves * 4, exact
  int r0 = row_start[node];
  int deg = row_start[node + 1] - r0;
  int last = r0 + deg - 1;

  uint4 rx = *(const uint4*)((const ushort*)xrh + (size_t)node*DIM + hl*8);
  h2 xr01 = u2h(rx.x), xr23 = u2h(rx.y), xr45 = u2h(rx.z), xr67 = u2h(rx.w);
  const float* ap = att + hl*8;
  float4 af0 = *(const float4*)(ap);
  float4 af1 = *(const float4*)(ap + 4);
  h2 a01 = {(_Float16)af0.x, (_Float16)af0.y};
  h2 a23 = {(_Float16)af0.z, (_Float16)af0.w};
  h2 a45 = {(_Float16)af1.x, (_Float16)af1.y};
  h2 a67 = {(_Float16)af1.z, (_Float16)af1.w};
  const h2 c02 = {(_Float16)0.2f, (_Float16)0.2f};

  float l = 0.f;
  float b0a=0,b1a=0,b2a=0,b3a=0,b4a=0,b5a=0,b6a=0,b7a=0;
  const ushort* xbase = (const ushort*)xlh + hl*8;

  // Divergent per 16-lane-group loop: groups with smaller deg retire early
  // (their lanes are exec-masked off -> no wasted loads/VALU). Edge order
  // within each node is unchanged vs the 4-deep version -> identical sums.
  for (int t = 0; t < deg; t += 8) {
    int idx[8];
    #pragma unroll
    for (int j = 0; j < 8; j++) {
      int rr = r0 + t + j;
      idx[j] = csr_src[rr <= last ? rr : last];
    }
    uint4 raw[8];
    #pragma unroll
    for (int j = 0; j < 8; j++)
      raw[j] = *(const uint4*)(xbase + (size_t)idx[j]*DIM);
    #pragma unroll
    for (int j = 0; j < 8; j++) {
      h2 v01 = u2h(raw[j].x), v23 = u2h(raw[j].y);
      h2 v45 = u2h(raw[j].z), v67 = u2h(raw[j].w);
      h2 s01 = v01 + xr01, s23 = v23 + xr23;
      h2 s45 = v45 + xr45, s67 = v67 + xr67;
      s01 = __builtin_elementwise_max(s01, s01 * c02);
      s23 = __builtin_elementwise_max(s23, s23 * c02);
      s45 = __builtin_elementwise_max(s45, s45 * c02);
      s67 = __builtin_elementwise_max(s67, s67 * c02);
      float p = __builtin_amdgcn_fdot2(s01, a01, 0.f, false);
      p = __builtin_amdgcn_fdot2(s23, a23, p, false);
      p = __builtin_amdgcn_fdot2(s45, a45, p, false);
      p = __builtin_amdgcn_fdot2(s67, a67, p, false);
      #pragma unroll
      for (int o = 1; o <= 8; o <<= 1) p += __shfl_xor(p, o, 64);
      float w = (t + j < deg) ? __expf(p) : 0.f;
      l += w;
      b0a = fmaf(w, (float)v01.x, b0a); b1a = fmaf(w, (float)v01.y, b1a);
      b2a = fmaf(w, (float)v23.x, b2a); b3a = fmaf(w, (float)v23.y, b3a);
      b4a = fmaf(w, (float)v45.x, b4a); b5a = fmaf(w, (float)v45.y, b5a);
      b6a = fmaf(w, (float)v67.x, b6a); b7a = fmaf(w, (float)v67.y, b7a);
    }
  }

  float inv = 1.f / fmaxf(l, 1e-16f);
  const float* bp = bias + hl*8;
  float4 c0 = *(const float4*)(bp);
  float4 c1 = *(const float4*)(bp + 4);
  float4 o0, o1;
  o0.x = fmaxf(fmaf(b0a, inv, c0.x), 0.f);
  o0.y = fmaxf(fmaf(b1a, inv, c0.y), 0.f);
  o0.z = fmaxf(fmaf(b2a, inv, c0.z), 0.f);
  o0.w = fmaxf(fmaf(b3a, inv, c0.w), 0.f);
  o1.x = fmaxf(fmaf(b4a, inv, c1.x), 0.f);
  o1.y = fmaxf(fmaf(b5a, inv, c1.y), 0.f);
  o1.z = fmaxf(fmaf(b6a, inv, c1.z), 0.f);
  o1.w = fmaxf(fmaf(b7a, inv, c1.w), 0.f);
  if (OUT == 0) {
    float* op = outf + (size_t)node*DIM + hl*8;
    *(float4*)(op)     = o0;
    *(float4*)(op + 4) = o1;
  } else {
    __half2 h0 = __floats2half2_rn(o0.x, o0.y);
    __half2 h1 = __floats2half2_rn(o0.z, o0.w);
    __half2 h2v = __floats2half2_rn(o1.x, o1.y);
    __half2 h3 = __floats2half2_rn(o1.z, o1.w);
    uint4 pk = make_uint4(*(uint*)&h0, *(uint*)&h1, *(uint*)&h2v, *(uint*)&h3);
    *(uint4*)((ushort*)outh + (size_t)node*DIM + hl*8) = pk;
  }
}

extern "C" void kernel_launch(void* const* d_in, const int* in_sizes, int n_in,
                              void* d_out, int out_size, void* d_ws, size_t ws_size,
                              hipStream_t stream)
{
  const float* node_fts = (const float*)d_in[0];
  const int*  edge_index = (const int*)d_in[1];
  const float* Wl1 = (const float*)d_in[2];
  const float* bl1 = (const float*)d_in[3];
  const float* Wr1 = (const float*)d_in[4];
  const float* br1 = (const float*)d_in[5];
  const float* att1 = (const float*)d_in[6];
  const float* bias1 = (const float*)d_in[7];
  const float* Wl2 = (const float*)d_in[8];
  const float* bl2 = (const float*)d_in[9];
  const float* Wr2 = (const float*)d_in[10];
  const float* br2 = (const float*)d_in[11];
  const float* att2 = (const float*)d_in[12];
  const float* bias2 = (const float*)d_in[13];
  const int* src = edge_index;
  const int* dst = edge_index + N_EDGES;

  char* ws = (char*)d_ws;
  __half* xlh = (__half*)ws;               ws += (size_t)N_NODES*DIM*2;
  __half* xrh = (__half*)ws;               ws += (size_t)N_NODES*DIM*2;
  __half* hh  = (__half*)ws;               ws += (size_t)N_NODES*DIM*2;
  _Float16* wb = (_Float16*)ws;            ws += 2*4*16*64*8*2;
  int* row_start   = (int*)ws;             ws += (N_NODES+1)*4;
  int* csr_src     = (int*)ws;             ws += (size_t)N_EDGES*4;
  int* bucket_cnt  = (int*)ws;             ws += KBUCKET*4;
  uint* bucketdata = (uint*)ws;            ws += (size_t)KBUCKET*BCAP*4;

  const int W_LAYER = 4*16*64*8;           // fp16 elems per layer of wb

  int gemm_blocks = (NGROUPS + 3) / 4;
  int gather_blocks = N_NODES / 16;        // 4 waves/block, 4 nodes/wave

  // ---- W fragment prep (also zeroes bucket_cnt; same-stream ordering
  //      guarantees it completes before bucket_scatter_k starts) ----
  prep_w<<<128, 64, 0, stream>>>(Wl1, Wr1, Wl2, Wr2, wb, bucket_cnt);

  // ---- CSR build (two-phase bucket radix, packed u32 payload) ----
  bucket_scatter_k<<<N_EDGES/EPB, 256, 0, stream>>>(src, dst, bucket_cnt, bucketdata);
  bucket_csr_k<<<KBUCKET, 256, 0, stream>>>(bucket_cnt, bucketdata, row_start, csr_src);

  // ---- layer 1 ----
  gemm_mfma<float><<<gemm_blocks, 256, 0, stream>>>(node_fts, wb, bl1, br1, xlh, xrh);
  gat_gather<1><<<gather_blocks, 256, 0, stream>>>(xlh, xrh, row_start, csr_src,
                                                   att1, bias1, nullptr, hh);
  // ---- layer 2 ----
  gemm_mfma<_Float16><<<gemm_blocks, 256, 0, stream>>>((const _Float16*)hh,
                                             wb + W_LAYER, bl2, br2, xlh, xrh);
  gat_gather<0><<<gather_blocks, 256, 0, stream>>>(xlh, xrh, row_start, csr_src,
                                                   att2, bias2, (float*)d_out, nullptr);
}

// Round 2
// 218.118 us; speedup vs baseline: 1.1492x; 1.1380x over previous
//
#include <hip/hip_runtime.h>
#include <hip/hip_bf16.h>
#include <hip/hip_fp16.h>

#define N_NODES 50000
#define N_EDGES 800000
#define DIM 128
#define NGROUPS (N_NODES / 16)                 // 3125 (exact)
#define LROW2 132                              // LDS row stride (floats)
#define KBUCKET 196                            // buckets of 256 nodes (dst>>8)
#define BCAP 5120                              // bucket capacity (mean 4096, ~16 sigma)
#define EPB 2000                               // edges per phase-A block (400 blocks)

typedef __attribute__((ext_vector_type(8))) _Float16 hfrag8;
typedef __attribute__((ext_vector_type(4))) float f32x4;
typedef _Float16 h2 __attribute__((ext_vector_type(2)));

__device__ __forceinline__ h2 u2h(uint u){ union{uint u; h2 h;} c; c.u = u; return c.h; }

// ---------------- CSR build phase A: bucket scatter ----------------
// bucketdata entry packed: (src << 8) | (dst & 255)   [src < 65536 fits 24b]

__global__ __launch_bounds__(256) void bucket_scatter_k(
    const int* __restrict__ src, const int* __restrict__ dst,
    int* __restrict__ bucket_cnt, uint* __restrict__ bucketdata)
{
  __shared__ int cnt[KBUCKET], base[KBUCKET], cur[KBUCKET];
  int tid = threadIdx.x;
  for (int t = tid; t < KBUCKET; t += 256) { cnt[t] = 0; cur[t] = 0; }
  __syncthreads();
  int e0 = blockIdx.x * EPB;
  int dreg[8];                                 // cache dst: read once, use twice
  #pragma unroll
  for (int it = 0; it < 8; it++) {
    int i = it*256 + tid;
    dreg[it] = (i < EPB) ? dst[e0 + i] : -1;
    if (i < EPB) atomicAdd(&cnt[dreg[it] >> 8], 1);
  }
  __syncthreads();
  for (int t = tid; t < KBUCKET; t += 256)
    base[t] = atomicAdd(&bucket_cnt[t], cnt[t]);
  __syncthreads();
  #pragma unroll
  for (int it = 0; it < 8; it++) {
    int i = it*256 + tid;
    if (i < EPB) {
      int s = src[e0 + i], d = dreg[it];
      int b = d >> 8;
      int r = atomicAdd(&cur[b], 1);
      bucketdata[(size_t)b * BCAP + base[b] + r] = ((uint)s << 8) | (uint)(d & 255);
    }
  }
}

// ---------------- W fragment prep (fp16) + bucket_cnt zeroing ----------------
// B-frag: lane holds B[k=(lane>>4)*8+j][n=lane&15].
__global__ __launch_bounds__(64) void prep_w(
    const float* __restrict__ Wl1, const float* __restrict__ Wr1,
    const float* __restrict__ Wl2, const float* __restrict__ Wr2,
    _Float16* __restrict__ wb, int* __restrict__ bucket_cnt)
{
  int bid = blockIdx.x;            // 2 layers * 4 C * 16 g = 128 blocks
  if (bid == 0) {                  // fold the memset dispatch in here
    for (int t = threadIdx.x; t < KBUCKET; t += 64) bucket_cnt[t] = 0;
  }
  int layer = bid >> 6, rest = bid & 63;
  int C = rest >> 4, g = rest & 15;
  int lane = threadIdx.x;
  int m = lane & 15, q = lane >> 4;
  int dim = g*16 + m;
  const float* W = layer ? (dim < 128 ? Wl2 : Wr2) : (dim < 128 ? Wl1 : Wr1);
  int dcol = dim & 127;
  _Float16 h[8];
  #pragma unroll
  for (int j = 0; j < 8; j++) {
    int k = C*32 + q*8 + j;
    h[j] = (_Float16)W[(size_t)k*DIM + dcol];
  }
  size_t off = ((size_t)bid*64 + lane)*8;
  *(hfrag8*)(wb + off) = *(hfrag8*)h;
}

// ---------------- merged: gemm layer1 (fp32 in) + CSR phase B ----------------
// blocks [0, KBUCKET): bucket_csr. blocks [KBUCKET, ...): MFMA gemm, 4 waves
// each owning one 16-node group. CSR work hides under the GEMM.
__global__ __launch_bounds__(256) void gemm1_csr_k(
    const float* __restrict__ x, const _Float16* __restrict__ wb,
    const float* __restrict__ bl, const float* __restrict__ br,
    __half* __restrict__ xlh, __half* __restrict__ xrh,
    const int* __restrict__ bucket_cnt, const uint* __restrict__ bucketdata,
    int* __restrict__ row_start, int* __restrict__ csr_src)
{
  __shared__ float lds[4][16*LROW2];   // 33.8 KB (gemm path)
  __shared__ int hist[256], cur[256];  // csr path
  __shared__ int wsumA[4], wsumB[4];
  int tid = threadIdx.x;

  if (blockIdx.x < KBUCKET) {
    // ---- bucket_csr path ----
    int b = blockIdx.x;
    int lane = tid & 63, w = tid >> 6;
    int vv = (tid < b) ? bucket_cnt[tid] : 0;
    #pragma unroll
    for (int off = 32; off > 0; off >>= 1) vv += __shfl_xor(vv, off, 64);
    if (lane == 0) wsumA[w] = vv;
    hist[tid] = 0;
    __syncthreads();
    int base_csr = wsumA[0] + wsumA[1] + wsumA[2] + wsumA[3];
    int cnt = bucket_cnt[b];
    int node0 = b << 8;
    const uint* bd = bucketdata + (size_t)b * BCAP;
    for (int i = tid; i < cnt; i += 256)
      atomicAdd(&hist[bd[i] & 255], 1);
    __syncthreads();
    int v = hist[tid];
    int inc = v;
    #pragma unroll
    for (int off = 1; off < 64; off <<= 1) {
      int y = __shfl_up(inc, off, 64);
      if (lane >= off) inc += y;
    }
    if (lane == 63) wsumB[w] = inc;
    __syncthreads();
    int wpre = 0;
    #pragma unroll
    for (int i = 0; i < 4; i++) if (i < w) wpre += wsumB[i];
    int excl = wpre + inc - v;
    int node = node0 + tid;
    if (node < N_NODES) row_start[node] = base_csr + excl;
    if (b == 0 && tid == 0) row_start[N_NODES] = N_EDGES;
    cur[tid] = excl;
    __syncthreads();
    for (int i = tid; i < cnt; i += 256) {
      uint p = bd[i];
      int r = atomicAdd(&cur[p & 255], 1);
      csr_src[base_csr + r] = (int)(p >> 8);
    }
    return;
  }

  // ---- gemm path (layer 1, fp32 input) ----
  int wv = tid >> 6, lane = tid & 63;
  int G = (blockIdx.x - KBUCKET) * 4 + wv;
  if (G >= NGROUPS) return;

  int m = lane & 15, q = lane >> 4;
  const float* xrow = x + (size_t)(G*16 + m)*DIM + q*8;

  f32x4 acc[16];
  #pragma unroll
  for (int g = 0; g < 16; g++) acc[g] = (f32x4)(0.f);

  #pragma unroll 1
  for (int C = 0; C < 4; C++) {
    float v[8];
    *(float4*)(v)     = *(const float4*)(xrow + C*32);
    *(float4*)(v + 4) = *(const float4*)(xrow + C*32 + 4);
    _Float16 hh[8];
    #pragma unroll
    for (int j = 0; j < 8; j++) hh[j] = (_Float16)v[j];
    hfrag8 ah = *(hfrag8*)hh;
    #pragma unroll
    for (int g = 0; g < 16; g++) {
      size_t boff = ((size_t)(C*16 + g)*64 + lane)*8;
      hfrag8 bh = *(const hfrag8*)(wb + boff);
      acc[g] = __builtin_amdgcn_mfma_f32_16x16x32_f16(ah, bh, acc[g], 0, 0, 0);
    }
  }

  // C/D: col = lane&15 (dim), row = (lane>>4)*4 + reg (node). LDS transpose.
  float* wlds = lds[wv];
  int dcol = (lane & 31) * 4;
  int rowsel = lane >> 5;
  #pragma unroll
  for (int half = 0; half < 2; half++) {
    #pragma unroll
    for (int g = 0; g < 8; g++) {
      #pragma unroll
      for (int r = 0; r < 4; r++)
        wlds[(q*4 + r)*LROW2 + g*16 + m] = acc[half*8 + g][r];
    }
    const float* B = half ? br : bl;
    ushort* outh = half ? (ushort*)xrh : (ushort*)xlh;
    float4 bv = *(const float4*)(B + dcol);
    #pragma unroll
    for (int it = 0; it < 8; it++) {
      int i = it*2 + rowsel;
      float4 vv = *(const float4*)(wlds + i*LROW2 + dcol);
      int node = G*16 + i;
      __half2 h0 = __floats2half2_rn(vv.x + bv.x, vv.y + bv.y);
      __half2 h1 = __floats2half2_rn(vv.z + bv.z, vv.w + bv.w);
      uint2 pk = make_uint2(*(uint*)&h0, *(uint*)&h1);
      *(uint2*)(outh + (size_t)node*DIM + dcol) = pk;
    }
  }
}

// ---------------- gather core: one node per 16-lane group --------------------
// Returns post-bias post-ReLU output slice (dims hl*8 .. hl*8+7) in o0,o1.
__device__ __forceinline__ void gather_core(
    int node, int hl,
    const __half* __restrict__ xlh, const __half* __restrict__ xrh,
    const int* __restrict__ row_start, const int* __restrict__ csr_src,
    const float* __restrict__ att, const float* __restrict__ bias,
    float4& o0, float4& o1)
{
  int r0 = row_start[node];
  int deg = row_start[node + 1] - r0;
  int last = r0 + deg - 1;

  uint4 rx = *(const uint4*)((const ushort*)xrh + (size_t)node*DIM + hl*8);
  h2 xr01 = u2h(rx.x), xr23 = u2h(rx.y), xr45 = u2h(rx.z), xr67 = u2h(rx.w);
  const float* ap = att + hl*8;
  float4 af0 = *(const float4*)(ap);
  float4 af1 = *(const float4*)(ap + 4);
  h2 a01 = {(_Float16)af0.x, (_Float16)af0.y};
  h2 a23 = {(_Float16)af0.z, (_Float16)af0.w};
  h2 a45 = {(_Float16)af1.x, (_Float16)af1.y};
  h2 a67 = {(_Float16)af1.z, (_Float16)af1.w};
  const h2 c02 = {(_Float16)0.2f, (_Float16)0.2f};

  float l = 0.f;
  float b0a=0,b1a=0,b2a=0,b3a=0,b4a=0,b5a=0,b6a=0,b7a=0;
  const ushort* xbase = (const ushort*)xlh + hl*8;

  for (int t = 0; t < deg; t += 8) {
    int idx[8];
    #pragma unroll
    for (int j = 0; j < 8; j++) {
      int rr = r0 + t + j;
      idx[j] = csr_src[rr <= last ? rr : last];
    }
    uint4 raw[8];
    #pragma unroll
    for (int j = 0; j < 8; j++)
      raw[j] = *(const uint4*)(xbase + (size_t)idx[j]*DIM);
    #pragma unroll
    for (int j = 0; j < 8; j++) {
      h2 v01 = u2h(raw[j].x), v23 = u2h(raw[j].y);
      h2 v45 = u2h(raw[j].z), v67 = u2h(raw[j].w);
      h2 s01 = v01 + xr01, s23 = v23 + xr23;
      h2 s45 = v45 + xr45, s67 = v67 + xr67;
      s01 = __builtin_elementwise_max(s01, s01 * c02);
      s23 = __builtin_elementwise_max(s23, s23 * c02);
      s45 = __builtin_elementwise_max(s45, s45 * c02);
      s67 = __builtin_elementwise_max(s67, s67 * c02);
      float p = __builtin_amdgcn_fdot2(s01, a01, 0.f, false);
      p = __builtin_amdgcn_fdot2(s23, a23, p, false);
      p = __builtin_amdgcn_fdot2(s45, a45, p, false);
      p = __builtin_amdgcn_fdot2(s67, a67, p, false);
      #pragma unroll
      for (int o = 1; o <= 8; o <<= 1) p += __shfl_xor(p, o, 64);
      float w = (t + j < deg) ? __expf(p) : 0.f;
      l += w;
      b0a = fmaf(w, (float)v01.x, b0a); b1a = fmaf(w, (float)v01.y, b1a);
      b2a = fmaf(w, (float)v23.x, b2a); b3a = fmaf(w, (float)v23.y, b3a);
      b4a = fmaf(w, (float)v45.x, b4a); b5a = fmaf(w, (float)v45.y, b5a);
      b6a = fmaf(w, (float)v67.x, b6a); b7a = fmaf(w, (float)v67.y, b7a);
    }
  }

  float inv = 1.f / fmaxf(l, 1e-16f);
  const float* bp = bias + hl*8;
  float4 c0 = *(const float4*)(bp);
  float4 c1 = *(const float4*)(bp + 4);
  o0.x = fmaxf(fmaf(b0a, inv, c0.x), 0.f);
  o0.y = fmaxf(fmaf(b1a, inv, c0.y), 0.f);
  o0.z = fmaxf(fmaf(b2a, inv, c0.z), 0.f);
  o0.w = fmaxf(fmaf(b3a, inv, c0.w), 0.f);
  o1.x = fmaxf(fmaf(b4a, inv, c1.x), 0.f);
  o1.y = fmaxf(fmaf(b5a, inv, c1.y), 0.f);
  o1.z = fmaxf(fmaf(b6a, inv, c1.z), 0.f);
  o1.w = fmaxf(fmaf(b7a, inv, c1.w), 0.f);
}

// ---------------- fused: gather layer1 + gemm layer2 -------------------------
// Block = 16 nodes (4 waves x 4 nodes). Gather output (fp16, same rounding as
// the old hh buffer) goes to swizzled LDS; the gemm phase splits the 16 output
// g-tiles across the 4 waves (4 MFMA-g x 4 C each). Kills the hh round-trip.
__global__ __launch_bounds__(256) void fused_g1_gemm2_k(
    const __half* __restrict__ xlh, const __half* __restrict__ xrh,
    const int* __restrict__ row_start, const int* __restrict__ csr_src,
    const float* __restrict__ att, const float* __restrict__ bias,
    const _Float16* __restrict__ wb2,
    const float* __restrict__ bl2, const float* __restrict__ br2,
    __half* __restrict__ xlh2, __half* __restrict__ xrh2)
{
  __shared__ ushort xs[16*128];     // 4 KB: swizzled fp16 input rows
  __shared__ ushort outs[16*256];   // 8 KB: fp16 output rows (xl|xr)
  int tid = threadIdx.x;
  int wv = tid >> 6, lane = tid & 63;
  int q4 = lane >> 4, hl = lane & 15;
  int nl = wv*4 + q4;
  int base = blockIdx.x * 16;

  // ---- gather phase (layer 1) ----
  float4 o0, o1;
  gather_core(base + nl, hl, xlh, xrh, row_start, csr_src, att, bias, o0, o1);
  __half2 p0 = __floats2half2_rn(o0.x, o0.y);
  __half2 p1 = __floats2half2_rn(o0.z, o0.w);
  __half2 p2 = __floats2half2_rn(o1.x, o1.y);
  __half2 p3 = __floats2half2_rn(o1.z, o1.w);
  uint4 pk = make_uint4(*(uint*)&p0, *(uint*)&p1, *(uint*)&p2, *(uint*)&p3);
  // row nl, byte hl*16, XOR-swizzled so gemm's ds_read_b128 is conflict-free
  *(uint4*)((char*)xs + nl*256 + ((hl*16) ^ ((nl&7)<<4))) = pk;
  __syncthreads();

  // ---- gemm phase (layer 2) ----
  int m = lane & 15, q = lane >> 4;
  f32x4 acc[4];
  #pragma unroll
  for (int g = 0; g < 4; g++) acc[g] = (f32x4)(0.f);
  #pragma unroll
  for (int C = 0; C < 4; C++) {
    hfrag8 ah = *(const hfrag8*)((const char*)xs + m*256 + ((C*64 + q*16) ^ ((m&7)<<4)));
    #pragma unroll
    for (int g = 0; g < 4; g++) {
      int gg = wv*4 + g;
      size_t boff = ((size_t)(C*16 + gg)*64 + lane)*8;
      hfrag8 bh = *(const hfrag8*)(wb2 + boff);
      acc[g] = __builtin_amdgcn_mfma_f32_16x16x32_f16(ah, bh, acc[g], 0, 0, 0);
    }
  }
  // epilogue: bias in f32 (same as standalone), RNE cvt, fp16 LDS transpose
  #pragma unroll
  for (int g = 0; g < 4; g++) {
    int gg = wv*4 + g;
    int dim = gg*16 + m;                       // 0..255 combined (xl|xr)
    float bv = (gg < 8) ? bl2[dim] : br2[dim - 128];
    #pragma unroll
    for (int r = 0; r < 4; r++) {
      int row = q*4 + r;                       // node within group
      __half hv = __float2half_rn(acc[g][r] + bv);
      outs[row*256 + gg*16 + m] = *(ushort*)&hv;
    }
  }
  __syncthreads();
  // cooperative coalesced writeout: 16 rows x 256 fp16 = 512 x 16B chunks
  #pragma unroll
  for (int p = 0; p < 2; p++) {
    int c = p*256 + tid;
    int row = c >> 5, off = c & 31;
    uint4 v = *(const uint4*)((const char*)outs + row*512 + off*16);
    int nodeo = base + row;
    int d0 = off*8;
    ushort* dstp = (d0 < 128) ? ((ushort*)xlh2 + (size_t)nodeo*DIM + d0)
                              : ((ushort*)xrh2 + (size_t)nodeo*DIM + (d0 - 128));
    *(uint4*)dstp = v;
  }
}

// ---------------- final gather (layer 2) -> fp32 output ----------------------
__global__ __launch_bounds__(256) void gat_gather2(
    const __half* __restrict__ xlh, const __half* __restrict__ xrh,
    const int* __restrict__ row_start, const int* __restrict__ csr_src,
    const float* __restrict__ att, const float* __restrict__ bias,
    float* __restrict__ outf)
{
  int wave = (blockIdx.x * 256 + threadIdx.x) >> 6;
  int lane = threadIdx.x & 63;
  int q4 = lane >> 4;
  int hl = lane & 15;
  int node = wave * 4 + q4;
  float4 o0, o1;
  gather_core(node, hl, xlh, xrh, row_start, csr_src, att, bias, o0, o1);
  float* op = outf + (size_t)node*DIM + hl*8;
  *(float4*)(op)     = o0;
  *(float4*)(op + 4) = o1;
}

extern "C" void kernel_launch(void* const* d_in, const int* in_sizes, int n_in,
                              void* d_out, int out_size, void* d_ws, size_t ws_size,
                              hipStream_t stream)
{
  const float* node_fts = (const float*)d_in[0];
  const int*  edge_index = (const int*)d_in[1];
  const float* Wl1 = (const float*)d_in[2];
  const float* bl1 = (const float*)d_in[3];
  const float* Wr1 = (const float*)d_in[4];
  const float* br1 = (const float*)d_in[5];
  const float* att1 = (const float*)d_in[6];
  const float* bias1 = (const float*)d_in[7];
  const float* Wl2 = (const float*)d_in[8];
  const float* bl2 = (const float*)d_in[9];
  const float* Wr2 = (const float*)d_in[10];
  const float* br2 = (const float*)d_in[11];
  const float* att2 = (const float*)d_in[12];
  const float* bias2 = (const float*)d_in[13];
  const int* src = edge_index;
  const int* dst = edge_index + N_EDGES;

  char* ws = (char*)d_ws;
  __half* xlh = (__half*)ws;               ws += (size_t)N_NODES*DIM*2;
  __half* xrh = (__half*)ws;               ws += (size_t)N_NODES*DIM*2;
  __half* xlh2 = (__half*)ws;              ws += (size_t)N_NODES*DIM*2;
  __half* xrh2 = (__half*)ws;              ws += (size_t)N_NODES*DIM*2;
  _Float16* wb = (_Float16*)ws;            ws += 2*4*16*64*8*2;
  int* row_start   = (int*)ws;             ws += (N_NODES+1)*4;
  int* csr_src     = (int*)ws;             ws += (size_t)N_EDGES*4;
  int* bucket_cnt  = (int*)ws;             ws += KBUCKET*4;
  uint* bucketdata = (uint*)ws;            ws += (size_t)KBUCKET*BCAP*4;

  const int W_LAYER = 4*16*64*8;           // fp16 elems per layer of wb

  int gemm_blocks = (NGROUPS + 3) / 4;     // 782
  int gather_blocks = N_NODES / 16;        // 3125

  // L1: W frags + zero bucket_cnt
  prep_w<<<128, 64, 0, stream>>>(Wl1, Wr1, Wl2, Wr2, wb, bucket_cnt);
  // L2: CSR phase A
  bucket_scatter_k<<<N_EDGES/EPB, 256, 0, stream>>>(src, dst, bucket_cnt, bucketdata);
  // L3: gemm layer1 + CSR phase B (merged; CSR hides under the GEMM)
  gemm1_csr_k<<<KBUCKET + gemm_blocks, 256, 0, stream>>>(
      node_fts, wb, bl1, br1, xlh, xrh,
      bucket_cnt, bucketdata, row_start, csr_src);
  // L4: gather layer1 + gemm layer2 fused (hh round-trip eliminated)
  fused_g1_gemm2_k<<<NGROUPS, 256, 0, stream>>>(
      xlh, xrh, row_start, csr_src, att1, bias1,
      wb + W_LAYER, bl2, br2, xlh2, xrh2);
  // L5: final gather layer2 -> fp32 out
  gat_gather2<<<gather_blocks, 256, 0, stream>>>(
      xlh2, xrh2, row_start, csr_src, att2, bias2, (float*)d_out);
}